// Round 1
// baseline (32847.958 us; speedup 1.0000x reference)
//
#include <hip/hip_runtime.h>
#include <math.h>

#define BB 256
#define TT 256
#define FD 8
#define ED 128
#define HD 256
#define NL10 10
#define WAVE_STEPS (TT + NL10 - 1)   /* 265 */

/* workspace layout (floats):
   h_buf: [10 layers][2 parity][BB][HD]   ping-pong hidden state
   c_buf: [10 layers][BB][HD]             cell state (in-place update)     */
#define H_BUF_SZ (NL10 * 2 * BB * HD)   /* 1,310,720 floats */
#define C_BUF_SZ (NL10 * BB * HD)       /*   655,360 floats */
#define WS_FLOATS (H_BUF_SZ + C_BUF_SZ) /* 7.86 MB */

__global__ __launch_bounds__(256) void zero_ws(float* ws) {
    size_t i = (size_t)blockIdx.x * blockDim.x + threadIdx.x;
    size_t stride = (size_t)gridDim.x * blockDim.x;
    for (; i < (size_t)WS_FLOATS; i += stride) ws[i] = 0.0f;
}

__device__ __forceinline__ float sigmoidf_(float v) {
    return 1.0f / (1.0f + expf(-v));
}

/* One wavefront step: computes layer-step (l, t = w - l) for all layers with
   0 <= t < T. Grid: 480 blocks = stack1 5*8jt*8bt + stack2 5*4jt*8bt.
   Block: 256 threads = 32 hidden (j) x 8 batch-rows; each thread does
   4 batches x 1 hidden x 4 gates = 16 accumulators. */
__global__ __launch_bounds__(256) void lstm_wave(
    int w,
    const float* __restrict__ x,
    const float* __restrict__ w_ih0_1,
    const float* __restrict__ w_ihr_1,
    const float* __restrict__ w_hh_1,
    const float* __restrict__ b_1,
    const float* __restrict__ w_ih0_2,
    const float* __restrict__ w_ihr_2,
    const float* __restrict__ w_hh_2,
    const float* __restrict__ b_2,
    float* __restrict__ ws,
    float* __restrict__ out)
{
    int bid = blockIdx.x;
    int l, jt, btile;
    if (bid < 320) {            /* stack 1: 5 layers x 8 jt x 8 bt */
        l = bid >> 6; int rem = bid & 63; jt = rem >> 3; btile = rem & 7;
    } else {                    /* stack 2: 5 layers x 4 jt x 8 bt */
        int b2 = bid - 320; l = 5 + (b2 >> 5); int rem = b2 & 31; jt = rem >> 3; btile = rem & 7;
    }
    int t = w - l;
    if (t < 0 || t >= TT) return;

    /* per-layer parameter selection (PyTorch gate order i,f,g,o in rows) */
    const float* wih; const float* whh; const float* bias;
    int din, hd;
    if (l == 0) {
        wih = w_ih0_1;                              whh = w_hh_1;
        bias = b_1;                                 din = FD;  hd = HD;
    } else if (l < 5) {
        wih = w_ihr_1 + (size_t)(l - 1) * 4 * HD * HD;
        whh = w_hh_1 + (size_t)l * 4 * HD * HD;
        bias = b_1 + l * 4 * HD;                    din = HD;  hd = HD;
    } else if (l == 5) {
        wih = w_ih0_2;                              whh = w_hh_2;
        bias = b_2;                                 din = HD;  hd = ED;
    } else {
        wih = w_ihr_2 + (size_t)(l - 6) * 4 * ED * ED;
        whh = w_hh_2 + (size_t)(l - 5) * 4 * ED * ED;
        bias = b_2 + (l - 5) * 4 * ED;              din = ED;  hd = ED;
    }

    float* hbuf = ws;
    float* cbuf = ws + H_BUF_SZ;

    const int jl   = threadIdx.x & 31;
    const int brow = threadIdx.x >> 5;        /* 0..7 */
    const int j    = jt * 32 + jl;            /* < hd by construction */
    const int b0   = btile * 32;

    float acc[4][4]; /* [batch m][gate g] */
    #pragma unroll
    for (int m = 0; m < 4; ++m)
        #pragma unroll
        for (int g = 0; g < 4; ++g)
            acc[m][g] = bias[g * hd + j];

    /* ---- input contribution: x_in @ W_ih^T ---- */
    const float* hin = hbuf + (((size_t)(l - 1) * 2 + (t & 1)) * BB * HD); /* l>0 */
    for (int k = 0; k < din; k += 4) {
        float4 wv[4];
        #pragma unroll
        for (int g = 0; g < 4; ++g)
            wv[g] = *(const float4*)&wih[(size_t)(g * hd + j) * din + k];
        float4 xv[4];
        #pragma unroll
        for (int m = 0; m < 4; ++m) {
            int b = b0 + brow + 8 * m;
            if (l == 0) xv[m] = *(const float4*)&x[((size_t)b * TT + t) * FD + k];
            else        xv[m] = *(const float4*)&hin[(size_t)b * HD + k];
        }
        #pragma unroll
        for (int m = 0; m < 4; ++m)
            #pragma unroll
            for (int g = 0; g < 4; ++g) {
                acc[m][g] = fmaf(wv[g].x, xv[m].x, acc[m][g]);
                acc[m][g] = fmaf(wv[g].y, xv[m].y, acc[m][g]);
                acc[m][g] = fmaf(wv[g].z, xv[m].z, acc[m][g]);
                acc[m][g] = fmaf(wv[g].w, xv[m].w, acc[m][g]);
            }
    }

    /* ---- recurrent contribution: h_{t-1} @ W_hh^T ---- */
    /* (t-1)&1 == 1 for t==0; that parity slot is zero-initialized and first
       written at t==1 (a later launch), so t==0 correctly reads h=0. */
    const float* hprev = hbuf + (((size_t)l * 2 + ((t - 1) & 1)) * BB * HD);
    for (int k = 0; k < hd; k += 4) {
        float4 wv[4];
        #pragma unroll
        for (int g = 0; g < 4; ++g)
            wv[g] = *(const float4*)&whh[(size_t)(g * hd + j) * hd + k];
        float4 xv[4];
        #pragma unroll
        for (int m = 0; m < 4; ++m) {
            int b = b0 + brow + 8 * m;
            xv[m] = *(const float4*)&hprev[(size_t)b * HD + k];
        }
        #pragma unroll
        for (int m = 0; m < 4; ++m)
            #pragma unroll
            for (int g = 0; g < 4; ++g) {
                acc[m][g] = fmaf(wv[g].x, xv[m].x, acc[m][g]);
                acc[m][g] = fmaf(wv[g].y, xv[m].y, acc[m][g]);
                acc[m][g] = fmaf(wv[g].z, xv[m].z, acc[m][g]);
                acc[m][g] = fmaf(wv[g].w, xv[m].w, acc[m][g]);
            }
    }

    /* ---- nonlinearity + state update ---- */
    float* hout = hbuf + (((size_t)l * 2 + (t & 1)) * BB * HD);
    float* crow = cbuf + (size_t)l * BB * HD;
    #pragma unroll
    for (int m = 0; m < 4; ++m) {
        int b = b0 + brow + 8 * m;
        float i_ = sigmoidf_(acc[m][0]);
        float f_ = sigmoidf_(acc[m][1]);
        float g_ = tanhf(acc[m][2]);
        float o_ = sigmoidf_(acc[m][3]);
        float c_old = crow[(size_t)b * HD + j];
        float c_new = fmaf(f_, c_old, i_ * g_);
        float h_new = o_ * tanhf(c_new);
        crow[(size_t)b * HD + j] = c_new;
        hout[(size_t)b * HD + j] = h_new;
        if (l == NL10 - 1 && t == TT - 1) out[b * ED + j] = h_new;
    }
}

extern "C" void kernel_launch(void* const* d_in, const int* in_sizes, int n_in,
                              void* d_out, int out_size, void* d_ws, size_t ws_size,
                              hipStream_t stream) {
    const float* x       = (const float*)d_in[0];
    const float* w_ih0_1 = (const float*)d_in[1];
    const float* w_ihr_1 = (const float*)d_in[2];
    const float* w_hh_1  = (const float*)d_in[3];
    const float* b_1     = (const float*)d_in[4];
    const float* w_ih0_2 = (const float*)d_in[5];
    const float* w_ihr_2 = (const float*)d_in[6];
    const float* w_hh_2  = (const float*)d_in[7];
    const float* b_2     = (const float*)d_in[8];
    float* ws  = (float*)d_ws;
    float* out = (float*)d_out;

    hipLaunchKernelGGL(zero_ws, dim3(512), dim3(256), 0, stream, ws);
    for (int w = 0; w < WAVE_STEPS; ++w) {
        hipLaunchKernelGGL(lstm_wave, dim3(480), dim3(256), 0, stream,
                           w, x, w_ih0_1, w_ihr_1, w_hh_1, b_1,
                           w_ih0_2, w_ihr_2, w_hh_2, b_2, ws, out);
    }
}

// Round 2
// 6466.798 us; speedup vs baseline: 5.0795x; 5.0795x over previous
//
#include <hip/hip_runtime.h>
#include <math.h>

typedef unsigned short u16;
typedef unsigned int   u32;
typedef __bf16 bf16x8 __attribute__((ext_vector_type(8)));
typedef float  f32x4  __attribute__((ext_vector_type(4)));

#define BB 256
#define TT 256
#define FD 8
#define ED 128
#define HD 256
#define NL10 10
#define WAVE_STEPS (TT + NL10 - 1)   /* 265 */

/* ws layout:
   [0, STATE_FLOATS) floats : h ping-pong [10][2][BB][HD] + c [10][BB][HD]
   then u16 region          : per-layer transposed bf16 weights, hi block then lo block
*/
#define H_BUF_SZ (NL10 * 2 * BB * HD)
#define C_BUF_SZ (NL10 * BB * HD)
#define STATE_FLOATS (H_BUF_SZ + C_BUF_SZ)

/* per-layer K (padded), din, u16 offsets/sizes of transposed weights */
__constant__ int    c_Kp[10]   = {288,512,512,512,512,384,256,256,256,256};
__constant__ int    c_din[10]  = {8,256,256,256,256,256,128,128,128,128};
__constant__ size_t c_woff[10] = {0ul,589824ul,1638400ul,2686976ul,3735552ul,
                                  4784128ul,5177344ul,5439488ul,5701632ul,5963776ul};
__constant__ int    c_sz[10]   = {294912,524288,524288,524288,524288,
                                  196608,131072,131072,131072,131072};

__device__ __forceinline__ u16 f2bf_hi(float f) {
    u32 u = __float_as_uint(f);
    u32 r = (u + 0x7FFFu + ((u >> 16) & 1u)) >> 16;
    return (u16)r;
}
__device__ __forceinline__ float bf2f(u16 h) {
    return __uint_as_float(((u32)h) << 16);
}
__device__ __forceinline__ float sigmoidf_(float v) {
    return 1.0f / (1.0f + expf(-v));
}

__global__ __launch_bounds__(256) void zero_state(float* ws) {
    size_t i = (size_t)blockIdx.x * blockDim.x + threadIdx.x;
    size_t stride = (size_t)gridDim.x * blockDim.x;
    for (; i < (size_t)STATE_FLOATS; i += stride) ws[i] = 0.0f;
}

/* Build transposed concat weights for one layer:
   dst[gj][k] : k<dinE -> wih[gj][k]; dinE<=k<hstart -> 0; k>=hstart -> whh[gj][k-hstart]
   hi block at dst, lo block at dst+sz. */
__global__ __launch_bounds__(256) void conv_weights(
    const float* __restrict__ wih, const float* __restrict__ whh, u16* __restrict__ dst,
    int total, int Kp, int dinE, int hstart, int hd_, int sz)
{
    int i = blockIdx.x * blockDim.x + threadIdx.x;
    int stride = gridDim.x * blockDim.x;
    for (; i < total; i += stride) {
        int gj = i / Kp, k = i - gj * Kp;
        float v = 0.0f;
        if (k < dinE) v = wih[(size_t)gj * dinE + k];
        else if (k >= hstart) v = whh[(size_t)gj * hd_ + (k - hstart)];
        u16 hi = f2bf_hi(v);
        float lof = v - bf2f(hi);
        dst[i]      = hi;
        dst[sz + i] = f2bf_hi(lof);
    }
}

/* One wavefront step. Grid 480 = stack1 5*(8jt*8bt) + stack2 5*(4jt*8bt).
   Block: 256 thr = 4 waves; wave w computes gate w's 32j x 32b tile via
   mfma_f32_16x16x32_bf16 with bf16x3 split; gates combined via LDS. */
__global__ __launch_bounds__(256) void lstm_wave_mfma(
    int w,
    const float* __restrict__ x,
    const float* __restrict__ b_1,
    const float* __restrict__ b_2,
    float* __restrict__ ws,
    float* __restrict__ out)
{
    int bid = blockIdx.x;
    int l, jt, bt;
    if (bid < 320) { l = bid >> 6; int r = bid & 63; jt = r >> 3; bt = r & 7; }
    else { int b2 = bid - 320; l = 5 + (b2 >> 5); int r = b2 & 31; jt = r >> 3; bt = r & 7; }
    int t = w - l;
    if (t < 0 || t >= TT) return;

    const int hd_  = (l < 5) ? HD : ED;
    const int Kp_  = c_Kp[l];
    const int dinL = c_din[l];
    const int nk   = Kp_ >> 5;
    const float* bias = (l < 5) ? (b_1 + l * 4 * HD) : (b_2 + (l - 5) * 4 * ED);

    float* hbuf = ws;
    float* cbuf = ws + H_BUF_SZ;
    const u16* wt2h = (const u16*)(ws + STATE_FLOATS) + c_woff[l];
    const u16* wt2l = wt2h + c_sz[l];
    const float* hin   = hbuf + ((size_t)(l - 1) * 2 + (t & 1)) * BB * HD;       /* l>0 */
    const float* hprev = hbuf + ((size_t)l * 2 + ((t - 1) & 1)) * BB * HD;

    /* LDS: A tiles [4g*32j][40] bf16 hi/lo, B tiles [32b][40] hi/lo, S exchange */
    __shared__ u16 Ah[128 * 40];
    __shared__ u16 Al[128 * 40];
    __shared__ u16 Bh[32 * 40];
    __shared__ u16 Bl[32 * 40];
    __shared__ float S[4][32][33];

    const int tid = threadIdx.x;

    u32 pa[16]; /* 4x uint4 prefetch: Ah p0, Ah p1, Al p0, Al p1 */
    float4 pb;

    auto do_load = [&](int kt) {
        int k0 = kt << 5;
        #pragma unroll
        for (int p = 0; p < 2; ++p) {
            int c = tid + 256 * p;
            int row = c >> 2, kc = c & 3;
            int g = row >> 5, j = row & 31;
            size_t si = (size_t)(g * hd_ + jt * 32 + j) * Kp_ + k0 + kc * 8;
            uint4 vh = *(const uint4*)(wt2h + si);
            uint4 vl = *(const uint4*)(wt2l + si);
            pa[p*4+0] = vh.x; pa[p*4+1] = vh.y; pa[p*4+2] = vh.z; pa[p*4+3] = vh.w;
            pa[8+p*4+0] = vl.x; pa[8+p*4+1] = vl.y; pa[8+p*4+2] = vl.z; pa[8+p*4+3] = vl.w;
        }
        {
            int brow = tid >> 3, kc = tid & 7;
            int k = k0 + kc * 4;
            int bG = bt * 32 + brow;
            float4 v = make_float4(0.f, 0.f, 0.f, 0.f);
            if (l == 0) {
                if (kt == 0) { if (kc < 2) v = *(const float4*)&x[((size_t)bG * TT + t) * FD + kc * 4]; }
                else v = *(const float4*)&hprev[(size_t)bG * HD + (k - 32)];
            } else {
                if (k < dinL) v = *(const float4*)&hin[(size_t)bG * HD + k];
                else          v = *(const float4*)&hprev[(size_t)bG * HD + (k - dinL)];
            }
            pb = v;
        }
    };
    auto do_write = [&]() {
        #pragma unroll
        for (int p = 0; p < 2; ++p) {
            int c = tid + 256 * p;
            int row = c >> 2, kc = c & 3;
            uint4 vh = make_uint4(pa[p*4+0], pa[p*4+1], pa[p*4+2], pa[p*4+3]);
            uint4 vl = make_uint4(pa[8+p*4+0], pa[8+p*4+1], pa[8+p*4+2], pa[8+p*4+3]);
            *(uint4*)&Ah[row * 40 + kc * 8] = vh;
            *(uint4*)&Al[row * 40 + kc * 8] = vl;
        }
        {
            int brow = tid >> 3, kc = tid & 7;
            u16 h0 = f2bf_hi(pb.x), h1 = f2bf_hi(pb.y), h2 = f2bf_hi(pb.z), h3 = f2bf_hi(pb.w);
            float q0 = pb.x - bf2f(h0), q1 = pb.y - bf2f(h1), q2 = pb.z - bf2f(h2), q3 = pb.w - bf2f(h3);
            uint2 ph = make_uint2((u32)h0 | ((u32)h1 << 16), (u32)h2 | ((u32)h3 << 16));
            uint2 pl = make_uint2((u32)f2bf_hi(q0) | ((u32)f2bf_hi(q1) << 16),
                                  (u32)f2bf_hi(q2) | ((u32)f2bf_hi(q3) << 16));
            *(uint2*)&Bh[brow * 40 + kc * 4] = ph;
            *(uint2*)&Bl[brow * 40 + kc * 4] = pl;
        }
    };

    f32x4 acc00 = {0.f,0.f,0.f,0.f}, acc01 = {0.f,0.f,0.f,0.f};
    f32x4 acc10 = {0.f,0.f,0.f,0.f}, acc11 = {0.f,0.f,0.f,0.f};

    const int lane = tid & 63;
    const int wv   = tid >> 6;      /* gate index 0..3 */
    const int r15  = lane & 15;
    const int kq   = lane >> 4;

    do_load(0);
    for (int kt = 0; kt < nk; ++kt) {
        __syncthreads();
        do_write();
        if (kt + 1 < nk) do_load(kt + 1);
        __syncthreads();

        bf16x8 ah0 = *(const bf16x8*)&Ah[(wv * 32 +      r15) * 40 + kq * 8];
        bf16x8 ah1 = *(const bf16x8*)&Ah[(wv * 32 + 16 + r15) * 40 + kq * 8];
        bf16x8 al0 = *(const bf16x8*)&Al[(wv * 32 +      r15) * 40 + kq * 8];
        bf16x8 al1 = *(const bf16x8*)&Al[(wv * 32 + 16 + r15) * 40 + kq * 8];
        bf16x8 bh0 = *(const bf16x8*)&Bh[(     r15) * 40 + kq * 8];
        bf16x8 bh1 = *(const bf16x8*)&Bh[(16 + r15) * 40 + kq * 8];
        bf16x8 bl0 = *(const bf16x8*)&Bl[(     r15) * 40 + kq * 8];
        bf16x8 bl1 = *(const bf16x8*)&Bl[(16 + r15) * 40 + kq * 8];

        acc00 = __builtin_amdgcn_mfma_f32_16x16x32_bf16(ah0, bh0, acc00, 0, 0, 0);
        acc01 = __builtin_amdgcn_mfma_f32_16x16x32_bf16(ah0, bh1, acc01, 0, 0, 0);
        acc10 = __builtin_amdgcn_mfma_f32_16x16x32_bf16(ah1, bh0, acc10, 0, 0, 0);
        acc11 = __builtin_amdgcn_mfma_f32_16x16x32_bf16(ah1, bh1, acc11, 0, 0, 0);
        acc00 = __builtin_amdgcn_mfma_f32_16x16x32_bf16(ah0, bl0, acc00, 0, 0, 0);
        acc01 = __builtin_amdgcn_mfma_f32_16x16x32_bf16(ah0, bl1, acc01, 0, 0, 0);
        acc10 = __builtin_amdgcn_mfma_f32_16x16x32_bf16(ah1, bl0, acc10, 0, 0, 0);
        acc11 = __builtin_amdgcn_mfma_f32_16x16x32_bf16(ah1, bl1, acc11, 0, 0, 0);
        acc00 = __builtin_amdgcn_mfma_f32_16x16x32_bf16(al0, bh0, acc00, 0, 0, 0);
        acc01 = __builtin_amdgcn_mfma_f32_16x16x32_bf16(al0, bh1, acc01, 0, 0, 0);
        acc10 = __builtin_amdgcn_mfma_f32_16x16x32_bf16(al1, bh0, acc10, 0, 0, 0);
        acc11 = __builtin_amdgcn_mfma_f32_16x16x32_bf16(al1, bh1, acc11, 0, 0, 0);
    }

    /* gate-exchange via LDS: S[gate][j][b]; D layout: col=lane&15, row=(lane>>4)*4+r */
    #pragma unroll
    for (int r = 0; r < 4; ++r) {
        S[wv][0  + kq * 4 + r][0  + r15] = acc00[r];
        S[wv][0  + kq * 4 + r][16 + r15] = acc01[r];
        S[wv][16 + kq * 4 + r][0  + r15] = acc10[r];
        S[wv][16 + kq * 4 + r][16 + r15] = acc11[r];
    }
    __syncthreads();

    const int jl = tid & 31, bq = tid >> 5;
    const int jG = jt * 32 + jl;
    const float bi_ = bias[0 * hd_ + jG];
    const float bf_ = bias[1 * hd_ + jG];
    const float bg_ = bias[2 * hd_ + jG];
    const float bo_ = bias[3 * hd_ + jG];
    float* crow = cbuf + (size_t)l * BB * HD;
    float* hout = hbuf + ((size_t)l * 2 + (t & 1)) * BB * HD;

    #pragma unroll
    for (int q = 0; q < 4; ++q) {
        int bL = bq * 4 + q;
        int bG = bt * 32 + bL;
        float i_ = sigmoidf_(S[0][jl][bL] + bi_);
        float f_ = sigmoidf_(S[1][jl][bL] + bf_);
        float g_ = tanhf   (S[2][jl][bL] + bg_);
        float o_ = sigmoidf_(S[3][jl][bL] + bo_);
        float c_old = crow[(size_t)bG * HD + jG];
        float c_new = fmaf(f_, c_old, i_ * g_);
        float h_new = o_ * tanhf(c_new);
        crow[(size_t)bG * HD + jG] = c_new;
        hout[(size_t)bG * HD + jG] = h_new;
        if (l == NL10 - 1 && t == TT - 1) out[bG * ED + jG] = h_new;
    }
}

extern "C" void kernel_launch(void* const* d_in, const int* in_sizes, int n_in,
                              void* d_out, int out_size, void* d_ws, size_t ws_size,
                              hipStream_t stream) {
    const float* x       = (const float*)d_in[0];
    const float* w_ih0_1 = (const float*)d_in[1];
    const float* w_ihr_1 = (const float*)d_in[2];
    const float* w_hh_1  = (const float*)d_in[3];
    const float* b_1     = (const float*)d_in[4];
    const float* w_ih0_2 = (const float*)d_in[5];
    const float* w_ihr_2 = (const float*)d_in[6];
    const float* w_hh_2  = (const float*)d_in[7];
    const float* b_2     = (const float*)d_in[8];
    float* ws  = (float*)d_ws;
    float* out = (float*)d_out;
    u16*   wt2 = (u16*)(ws + STATE_FLOATS);

    static const size_t hwoff[10] = {0ul,589824ul,1638400ul,2686976ul,3735552ul,
                                     4784128ul,5177344ul,5439488ul,5701632ul,5963776ul};
    static const int    hsz[10]   = {294912,524288,524288,524288,524288,
                                     196608,131072,131072,131072,131072};

    hipLaunchKernelGGL(zero_state, dim3(256), dim3(256), 0, stream, ws);

    for (int l = 0; l < NL10; ++l) {
        const float *wih, *whh; int M, Kp, dinE, hstart, hd_;
        if (l == 0)      { wih = w_ih0_1; whh = w_hh_1; M = 1024; Kp = 288; dinE = 8;   hstart = 32;  hd_ = 256; }
        else if (l < 5)  { wih = w_ihr_1 + (size_t)(l-1)*1024*256; whh = w_hh_1 + (size_t)l*1024*256;
                           M = 1024; Kp = 512; dinE = 256; hstart = 256; hd_ = 256; }
        else if (l == 5) { wih = w_ih0_2; whh = w_hh_2; M = 512; Kp = 384; dinE = 256; hstart = 256; hd_ = 128; }
        else             { wih = w_ihr_2 + (size_t)(l-6)*512*128; whh = w_hh_2 + (size_t)(l-5)*512*128;
                           M = 512; Kp = 256; dinE = 128; hstart = 128; hd_ = 128; }
        hipLaunchKernelGGL(conv_weights, dim3(128), dim3(256), 0, stream,
                           wih, whh, wt2 + hwoff[l], M * Kp, Kp, dinE, hstart, hd_, hsz[l]);
    }

    for (int w = 0; w < WAVE_STEPS; ++w) {
        hipLaunchKernelGGL(lstm_wave_mfma, dim3(480), dim3(256), 0, stream,
                           w, x, b_1, b_2, ws, out);
    }
}